// Round 4
// baseline (86.237 us; speedup 1.0000x reference)
//
#include <hip/hip_runtime.h>
#include <hip/hip_bf16.h>

// MDCA: for each of 4 CAMs [B=128, C=1000, H=14, W=14]:
//   avg_conf[c]  = mean over (b,h,w) of cam[b,c,h,w]
//   avg_count[c] = bincount(target, C)[c] / B
//   out[cam] = mean_c |avg_conf[c] - avg_count[c]|
//
// R3: pure linear streaming. A wave sweeps a CONTIGUOUS run of 3136 float4
// (= exactly 64 segments of 49 float4 = 64 (b,c) cells) in 49 coalesced
// 1 KB instructions. Per instruction the 64 lanes span <=3 segments
// (boundaries at f % 49 == 0, wave-uniform): 6-step shfl_up inclusive scan,
// readlane-extract the <=3 partials, predicated-add into the owning lane
// (lane l accumulates relative segment l). One coalesced 256 B store per
// run. No b-striding anywhere -> copy-bench-shaped traffic.
// Deterministic: private accumulators, fixed order, no float atomics.

constexpr int B    = 128;
constexpr int C    = 1000;
constexpr int HW   = 196;        // 14*14
constexpr int HW4  = 49;         // float4 per (b,c) segment
constexpr int NSEG = B * C;      // 128000 segments per cam
constexpr int NF4  = NSEG * HW4; // 6,272,000 float4 per cam
constexpr int RUN4 = 64 * HW4;   // 3136 float4 per run (64 segments)
constexpr int NRUN = NF4 / RUN4; // 2000 runs per cam (exact)

__device__ __forceinline__ float lane_read(float v, int src) {
    // src is wave-uniform -> v_readlane_b32 (no LDS-pipe traffic)
    return __int_as_float(__builtin_amdgcn_readlane(__float_as_int(v), src));
}

// grid (NRUN/4, ncam), block 256 = 4 independent waves (no barriers).
// Wave w of block handles run = blockIdx.x*4 + w of cam cam_base+blockIdx.y.
__global__ __launch_bounds__(256) void stage1_kernel(
    const float* __restrict__ c0, const float* __restrict__ c1,
    const float* __restrict__ c2, const float* __restrict__ c3,
    float* __restrict__ segsum, int cam_base)
{
    const int lane = threadIdx.x & 63;
    const int run  = blockIdx.x * 4 + (threadIdx.x >> 6);
    const int cam  = cam_base + blockIdx.y;
    const float* __restrict__ src =
        (cam == 0) ? c0 : (cam == 1) ? c1 : (cam == 2) ? c2 : c3;

    const float4* __restrict__ p =
        reinterpret_cast<const float4*>(src) + (size_t)run * RUN4 + lane;

    float acc = 0.0f;
    #pragma unroll 7
    for (int i = 0; i < 49; ++i) {
        const float4 v = p[i * 64];
        float sc = (v.x + v.y) + (v.z + v.w);

        // inclusive scan over the wave
        #pragma unroll
        for (int off = 1; off < 64; off <<= 1) {
            const float y = __shfl_up(sc, off, 64);
            if (lane >= off) sc += y;
        }

        // wave-uniform segment geometry for this 64-f4 window:
        // window base F = i*64 (run base = 0 mod 49); r = F % 49.
        const int r  = (15 * i) % 49;        // 64 = 15 (mod 49)
        const int l1 = 49 - r;               // first boundary lane, in [1,49]
        const int g0 = (64 * i) / 49;        // rel. segment of lane 0
        const int bx = (l1 + 48 > 63) ? 63 : (l1 + 48);

        const float SA = lane_read(sc, l1 - 1);  // sum lanes [0, l1)
        const float SB = lane_read(sc, bx);      // sum lanes [0, min(l1+49,64))
        const float ST = lane_read(sc, 63);      // total

        if (lane == g0)     acc += SA;           // tail of segment g0
        if (lane == g0 + 1) acc += SB - SA;      // segment g0+1 piece
        if (lane == g0 + 2) acc += ST - SB;      // segment g0+2 piece (or +0)
    }

    // lane l owns relative segment l of this run; g = run*64 + l = b*1000 + c
    segsum[(size_t)blockIdx.y * NSEG + (size_t)run * 64 + lane] = acc;
}

// grid = ncam blocks, 1024 threads. Fold 128 b's per class, histogram,
// block-reduce |avg_conf - avg_count|, write out[cam_base + slot].
__global__ __launch_bounds__(1024) void stage2_kernel(
    const float* __restrict__ segsum, const int* __restrict__ target,
    float* __restrict__ out, int cam_base)
{
    __shared__ int   cnt[C];
    __shared__ float red[16];

    const int slot = blockIdx.x;
    const int tid  = threadIdx.x;

    for (int i = tid; i < C; i += 1024) cnt[i] = 0;
    __syncthreads();
    if (tid < B) atomicAdd(&cnt[target[tid]], 1);
    __syncthreads();

    float a = 0.0f;
    if (tid < C) {
        const float* __restrict__ q = segsum + (size_t)slot * NSEG + tid;
        float t = 0.0f;
        #pragma unroll 8
        for (int b = 0; b < B; ++b) t += q[b * 1000];
        a = fabsf(t * (1.0f / (float)(B * HW))
                  - (float)cnt[tid] * (1.0f / (float)B));
    }

    #pragma unroll
    for (int off = 32; off > 0; off >>= 1)
        a += __shfl_down(a, off, 64);
    if ((tid & 63) == 0) red[tid >> 6] = a;
    __syncthreads();
    if (tid == 0) {
        float s = 0.0f;
        #pragma unroll
        for (int w = 0; w < 16; ++w) s += red[w];
        out[cam_base + slot] = s * (1.0f / (float)C);
    }
}

extern "C" void kernel_launch(void* const* d_in, const int* in_sizes, int n_in,
                              void* d_out, int out_size, void* d_ws, size_t ws_size,
                              hipStream_t stream) {
    const float* c0 = (const float*)d_in[0];
    const float* c1 = (const float*)d_in[1];
    const float* c2 = (const float*)d_in[2];
    const float* c3 = (const float*)d_in[3];
    const int*   target = (const int*)d_in[4];
    float*       out    = (float*)d_out;
    float*       segsum = (float*)d_ws;

    const size_t need4 = (size_t)4 * NSEG * sizeof(float);  // 2,048,000 B

    if (ws_size >= need4) {
        dim3 g1(NRUN / 4, 4);
        stage1_kernel<<<g1, 256, 0, stream>>>(c0, c1, c2, c3, segsum, 0);
        stage2_kernel<<<4, 1024, 0, stream>>>(segsum, target, out, 0);
    } else {
        // 2 cams at a time in 1,024,000 B (known-safe ws footprint)
        dim3 g1(NRUN / 4, 2);
        stage1_kernel<<<g1, 256, 0, stream>>>(c0, c1, c2, c3, segsum, 0);
        stage2_kernel<<<2, 1024, 0, stream>>>(segsum, target, out, 0);
        stage1_kernel<<<g1, 256, 0, stream>>>(c0, c1, c2, c3, segsum, 2);
        stage2_kernel<<<2, 1024, 0, stream>>>(segsum, target, out, 2);
    }
}